// Round 1
// baseline (98.735 us; speedup 1.0000x reference)
//
#include <hip/hip_runtime.h>

// BilinearJoints: closed-form 6x6 expm.
// M = [[A dt, B dt, 0],[0,0,I],[0,0,0]]  (A,B 2x2) =>
//   expM[:2,:2]   = exp(A dt)
//   expM[:2,2:4]  = phi1(A dt) B dt,  phi1(X) = (e^X - I) X^-1
//   Bd0@U0 + Bd1@U0 = expM[:2,2:4] @ U0   (phi2 terms cancel)
// A = [[0,1],[A10,A11]]; for any analytic f, f(A dt) = alpha*I + beta*(A dt)
// with alpha,beta from eigenvalues lambda = s +/- sqrt(Delta),
//   s = A11*dt/2, d = -A10*dt^2, Delta = s^2 - d.

constexpr int BATCH = 16384;
constexpr int NJ = 64;
constexpr int NM = 8;

__global__ __launch_bounds__(256) void bilinear_joints_kernel(
    const float* __restrict__ SS,
    const float* __restrict__ Alphas,
    const float* __restrict__ K0s,
    const float* __restrict__ K1s,
    const float* __restrict__ L0s,
    const float* __restrict__ L1s,
    const float* __restrict__ Ms,
    const float* __restrict__ Iarr,
    const float* __restrict__ Bjarr,
    const float* __restrict__ Kjarr,
    float* __restrict__ out0,
    float* __restrict__ out1)
{
    const float dt = 0.0166667f;
    const int idx = blockIdx.x * blockDim.x + threadIdx.x;  // b*NJ + j
    if (idx >= BATCH * NJ) return;
    const int j = idx & (NJ - 1);

    // --- vector loads (all 16B/8B aligned) ---
    const float2 ss  = *reinterpret_cast<const float2*>(SS + 2 * idx);
    const float4 a0v = *reinterpret_cast<const float4*>(Alphas + 8 * idx);
    const float4 a1v = *reinterpret_cast<const float4*>(Alphas + 8 * idx + 4);
    const float4 K0a = *reinterpret_cast<const float4*>(K0s + 8 * j);
    const float4 K0b = *reinterpret_cast<const float4*>(K0s + 8 * j + 4);
    const float4 K1a = *reinterpret_cast<const float4*>(K1s + 8 * j);
    const float4 K1b = *reinterpret_cast<const float4*>(K1s + 8 * j + 4);
    const float4 L0a = *reinterpret_cast<const float4*>(L0s + 8 * j);
    const float4 L0b = *reinterpret_cast<const float4*>(L0s + 8 * j + 4);
    const float4 L1a = *reinterpret_cast<const float4*>(L1s + 8 * j);
    const float4 L1b = *reinterpret_cast<const float4*>(L1s + 8 * j + 4);
    const float4 Msa = *reinterpret_cast<const float4*>(Ms + 8 * j);
    const float4 Msb = *reinterpret_cast<const float4*>(Ms + 8 * j + 4);

    const float Iv   = Iarr[j];
    const float Bjv  = Bjarr[j];
    const float Kjv  = Kjarr[j];
    const float invI = 1.0f / Iv;

    const float al[NM] = {a0v.x, a0v.y, a0v.z, a0v.w, a1v.x, a1v.y, a1v.z, a1v.w};
    const float k0[NM] = {K0a.x, K0a.y, K0a.z, K0a.w, K0b.x, K0b.y, K0b.z, K0b.w};
    const float k1[NM] = {K1a.x, K1a.y, K1a.z, K1a.w, K1b.x, K1b.y, K1b.z, K1b.w};
    const float l0[NM] = {L0a.x, L0a.y, L0a.z, L0a.w, L0b.x, L0b.y, L0b.z, L0b.w};
    const float l1[NM] = {L1a.x, L1a.y, L1a.z, L1a.w, L1b.x, L1b.y, L1b.z, L1b.w};
    const float ms[NM] = {Msa.x, Msa.y, Msa.z, Msa.w, Msb.x, Msb.y, Msb.z, Msb.w};

    const float absSS0 = fabsf(ss.x);

    float ksum = 0.0f, bacc = 0.0f;
#pragma unroll
    for (int m = 0; m < NM; ++m) {
        const float a  = fminf(fmaxf(al[m], 0.0f), 1.0f);
        const float kk = fmaf(k1[m], a, k0[m]);               // K0 + K1*a
        const float mv = ms[m];
        ksum = fmaf(kk * mv, mv, ksum);                        // += kk*Ms^2
        const float lt = fmaf(l1[m], a, l0[m]) - absSS0 * mv;  // L0+L1*a-|SS0*Ms|
        const float bf = fmaf(kk, lt, k1[m] * l1[m] * a * a);  // B_F
        bacc = fmaf(bf, mv, bacc);                             // += B_F*Ms
    }

    const float B10 = bacc * invI;
    const float A10 = -(ksum + Kjv) * invI;
    const float Dmp = 2.0f * sqrtf(ksum * Iv);
    const float A11 = -(Dmp + Bjv) * invI;

    // f(A dt) = alpha*I + beta*(A dt) for f in {exp, phi1}
    const float t = A11 * dt;
    const float s = 0.5f * t;
    const float d = -A10 * dt * dt;          // det(A dt) > 0 here (Kj >= 0.5)
    const float Delta = s * s - d;
    const float es = __expf(s);

    float alphaE, betaE, alphaP, betaP;
    if (Delta < 0.0f) {
        // complex pair: lambda = s +/- i r, s^2 + r^2 = d
        const float r  = sqrtf(-Delta);
        float si, co;
        __sincosf(r, &si, &co);
        const float sinc = (r > 1e-6f) ? si / r : 1.0f;
        betaE  = es * sinc;
        alphaE = es * co - betaE * s;
        const float invd = 1.0f / d;
        betaP = (s * es * sinc - es * co + 1.0f) * invd;
        const float ref1 = (s * (es * co - 1.0f) + r * r * es * sinc) * invd;
        alphaP = ref1 - betaP * s;
    } else {
        // real pair: lambda = s +/- r
        const float r  = sqrtf(Delta);
        const float er = __expf(r);
        const float ier = 1.0f / er;
        const float ch = 0.5f * (er + ier);
        const float sh = 0.5f * (er - ier);
        const float sinch = (r > 1e-6f) ? sh / r : 1.0f;
        betaE  = es * sinch;
        alphaE = es * ch - betaE * s;
        const float lam1 = s + r, lam2 = s - r;
        const float f1 = (fabsf(lam1) > 1e-6f) ? expm1f(lam1) / lam1 : 1.0f + 0.5f * lam1;
        const float f2 = (fabsf(lam2) > 1e-6f) ? expm1f(lam2) / lam2 : 1.0f + 0.5f * lam2;
        if (r > 1e-5f) {
            betaP = (f1 - f2) * (0.5f / r);
        } else {
            const float s2 = s * s;
            betaP = (s2 > 1e-12f) ? (es * (s - 1.0f) + 1.0f) / s2 : 0.5f;
        }
        alphaP = 0.5f * (f1 + f2) - betaP * s;
    }

    // Ad = alphaE*I + betaE*(A dt)
    const float Ad00 = alphaE;
    const float Ad01 = betaE * dt;
    const float Ad10 = betaE * A10 * dt;
    const float Ad11 = alphaE + betaE * A11 * dt;

    // w = phi1(A dt) @ (0, B10*dt)
    const float c1 = B10 * dt;
    const float w0 = betaP * dt * c1;
    const float w1 = (alphaP + betaP * A11 * dt) * c1;

    const float o0 = fmaf(Ad00, ss.x, fmaf(Ad01, ss.y, w0));
    const float o1 = fmaf(Ad10, ss.x, fmaf(Ad11, ss.y, w1));

    out0[idx] = o0;
    float2 o; o.x = o0; o.y = o1;
    *reinterpret_cast<float2*>(out1 + 2 * idx) = o;
}

extern "C" void kernel_launch(void* const* d_in, const int* in_sizes, int n_in,
                              void* d_out, int out_size, void* d_ws, size_t ws_size,
                              hipStream_t stream) {
    const float* SS     = (const float*)d_in[0];
    const float* Alphas = (const float*)d_in[1];
    const float* K0s    = (const float*)d_in[2];
    const float* K1s    = (const float*)d_in[3];
    const float* L0s    = (const float*)d_in[4];
    const float* L1s    = (const float*)d_in[5];
    const float* Msp    = (const float*)d_in[6];
    const float* Iarr   = (const float*)d_in[7];
    const float* Bjarr  = (const float*)d_in[8];
    const float* Kjarr  = (const float*)d_in[9];

    float* out0 = (float*)d_out;                  // (BATCH, NJ)
    float* out1 = out0 + BATCH * NJ;              // (BATCH, NJ, 2)

    const int total = BATCH * NJ;
    const int block = 256;
    const int grid = (total + block - 1) / block; // 4096 blocks

    bilinear_joints_kernel<<<grid, block, 0, stream>>>(
        SS, Alphas, K0s, K1s, L0s, L1s, Msp, Iarr, Bjarr, Kjarr, out0, out1);
}